// Round 1
// baseline (618.012 us; speedup 1.0000x reference)
//
#include <hip/hip_runtime.h>

typedef __bf16 bf16;
typedef __attribute__((ext_vector_type(8))) __bf16 bf16x8;
typedef __attribute__((ext_vector_type(4))) __bf16 bf16x4;
typedef __attribute__((ext_vector_type(4))) float f32x4;

#define B_  32
#define S_  2048
#define DC  1024
#define DQ  1024
#define H_  512
#define M_  (B_*S_)        // 65536 flattened (b,s) rows

#define BM  128
#define BN  128
#define BK  32
#define LDT 40             // LDS row stride in halfwords (32 data + 8 pad -> 2-way bank alias, free)

// ---------- Kernel T: Wc (W1[:1024]) -> bf16, transposed to [h][k] ----------
__global__ __launch_bounds__(256) void k_wconv(const float* __restrict__ W1,
                                               bf16* __restrict__ WcT) {
    int idx = blockIdx.x * 256 + threadIdx.x;      // 0..524287
    int h = idx >> 10;
    int k = idx & 1023;
    WcT[idx] = (bf16)W1[(size_t)k * H_ + h];       // strided read, L2 absorbs (2 MB)
}

// ---------- Kernel Q: qb[b][h] = query[b,:]·Wq[:,h] + b1[h] (fp32) ----------
__global__ __launch_bounds__(512) void k_qb(const float* __restrict__ query,
                                            const float* __restrict__ W1,
                                            const float* __restrict__ b1,
                                            float* __restrict__ qb) {
    int b = blockIdx.x, tid = threadIdx.x;
    __shared__ float q[DQ];
    q[tid]       = query[(size_t)b * DQ + tid];
    q[tid + 512] = query[(size_t)b * DQ + tid + 512];
    __syncthreads();
    float acc = b1[tid];
    const float* w = W1 + (size_t)DC * H_ + tid;   // Wq[d][tid] at w[d*512]
    #pragma unroll 8
    for (int d = 0; d < DQ; ++d)
        acc = fmaf(q[d], w[(size_t)d * H_], acc);
    qb[(size_t)b * H_ + tid] = acc;
}

// ---------- Kernel G: score partials = tanh(ctx@Wc + qb)·w2 ----------
// Grid (512, 4): mblk covers 128 rows (one batch each, 2048%128==0), nblk 128 of 512 h-cols.
// 4 waves in 2x2 grid, each 64x64 via 16x16x32 bf16 MFMA.
__global__ __launch_bounds__(256) void k_gemm(const float* __restrict__ ctx,
                                              const bf16*  __restrict__ WcT,
                                              const float* __restrict__ qb,
                                              const float* __restrict__ W2,
                                              float* __restrict__ score_part) {
    __shared__ bf16 As[BM * LDT];      // 10240 B
    __shared__ bf16 Bs[BN * LDT];      // 10240 B
    __shared__ float qs[BN];
    __shared__ float ws2[BN];

    const int tid  = threadIdx.x;
    const int mblk = blockIdx.x;               // 0..511
    const int nblk = blockIdx.y;               // 0..3
    const size_t row_base = (size_t)mblk * BM; // flattened (b,s) row
    const int b        = (mblk * BM) >> 11;    // /2048
    const int col_base = nblk * BN;

    if (tid < BN) {
        qs[tid]  = qb[(size_t)b * H_ + col_base + tid];
        ws2[tid] = W2[col_base + tid];
    }

    const int lane = tid & 63;
    const int wave = tid >> 6;
    const int wm   = wave & 1;
    const int wn   = wave >> 1;
    const int l16  = lane & 15;
    const int quad = lane >> 4;                // 0..3

    f32x4 acc[4][4] = {};

    const int tmA = tid >> 3;                  // 0..31
    const int tkA = (tid & 7) * 4;             // 0..28

    for (int k0 = 0; k0 < DC; k0 += BK) {
        // Stage A: 128x32 fp32 ctx -> bf16 LDS (row-major, padded)
        #pragma unroll
        for (int i = 0; i < 4; ++i) {
            int m = tmA + 32 * i;
            const float4 v = *(const float4*)(ctx + (row_base + m) * (size_t)DC + k0 + tkA);
            bf16x4 pk = { (bf16)v.x, (bf16)v.y, (bf16)v.z, (bf16)v.w };
            *(bf16x4*)(&As[m * LDT + tkA]) = pk;
        }
        // Stage B: 128 cols x 32 k of WcT (already [h][k]) -> LDS [col][k]
        #pragma unroll
        for (int i = 0; i < 2; ++i) {
            int c   = tid + 256 * i;           // 0..511
            int col = c >> 2;                  // 0..127
            int kk  = (c & 3) * 8;             // 0,8,16,24
            bf16x8 v = *(const bf16x8*)(WcT + (size_t)(col_base + col) * DC + k0 + kk);
            *(bf16x8*)(&Bs[col * LDT + kk]) = v;
        }
        __syncthreads();

        bf16x8 aF[4], bF[4];
        #pragma unroll
        for (int mf = 0; mf < 4; ++mf)
            aF[mf] = *(const bf16x8*)(&As[(wm * 64 + mf * 16 + l16) * LDT + quad * 8]);
        #pragma unroll
        for (int nf = 0; nf < 4; ++nf)
            bF[nf] = *(const bf16x8*)(&Bs[(wn * 64 + nf * 16 + l16) * LDT + quad * 8]);
        #pragma unroll
        for (int mf = 0; mf < 4; ++mf)
            #pragma unroll
            for (int nf = 0; nf < 4; ++nf)
                acc[mf][nf] = __builtin_amdgcn_mfma_f32_16x16x32_bf16(aF[mf], bF[nf], acc[mf][nf], 0, 0, 0);
        __syncthreads();
    }

    // Epilogue: per row, sum over this block's 128 cols of tanh(acc+qb)*w2
    float qv[4], wv[4];
    #pragma unroll
    for (int nf = 0; nf < 4; ++nf) {
        int c = wn * 64 + nf * 16 + l16;
        qv[nf] = qs[c];
        wv[nf] = ws2[c];
    }
    const int slot = nblk * 2 + wn;            // 0..7, deterministic writer per row
    float* sp = score_part + (size_t)slot * M_;
    #pragma unroll
    for (int mf = 0; mf < 4; ++mf) {
        #pragma unroll
        for (int r = 0; r < 4; ++r) {
            float s = 0.0f;
            #pragma unroll
            for (int nf = 0; nf < 4; ++nf) {
                float x = acc[mf][nf][r] + qv[nf];
                // tanh(x) = 1 - 2/(1+exp(2x)); saturates correctly at +/-inf
                float t = 1.0f - 2.0f / (1.0f + __expf(2.0f * x));
                s = fmaf(t, wv[nf], s);
            }
            // reduce over the 16 cols held by lanes differing in bits 0..3
            s += __shfl_xor(s, 1);
            s += __shfl_xor(s, 2);
            s += __shfl_xor(s, 4);
            s += __shfl_xor(s, 8);
            if (l16 == 0) {
                size_t row = row_base + wm * 64 + mf * 16 + quad * 4 + r;
                sp[row] = s;
            }
        }
    }
}

// ---------- Kernel S: sum partials + b2, mask, softmax per batch row ----------
__global__ __launch_bounds__(256) void k_softmax(const float* __restrict__ part,
                                                 const float* __restrict__ b2,
                                                 const int*   __restrict__ mask,
                                                 float* __restrict__ p_out) {
    int b = blockIdx.x, tid = threadIdx.x;
    __shared__ float red[256];
    float loc[8];
    float b2v = b2[0];
    float mx = -1e30f;
    #pragma unroll
    for (int i = 0; i < 8; ++i) {
        size_t r = (size_t)b * S_ + i * 256 + tid;
        float v = 0.0f;
        #pragma unroll
        for (int slot = 0; slot < 8; ++slot)
            v += part[(size_t)slot * M_ + r];
        v += b2v;
        if (mask[r] == 0) v = -10000.0f;
        loc[i] = v;
        mx = fmaxf(mx, v);
    }
    red[tid] = mx; __syncthreads();
    for (int o = 128; o > 0; o >>= 1) {
        if (tid < o) red[tid] = fmaxf(red[tid], red[tid + o]);
        __syncthreads();
    }
    mx = red[0]; __syncthreads();
    float se = 0.0f;
    #pragma unroll
    for (int i = 0; i < 8; ++i) {
        float e = __expf(loc[i] - mx);
        loc[i] = e;
        se += e;
    }
    red[tid] = se; __syncthreads();
    for (int o = 128; o > 0; o >>= 1) {
        if (tid < o) red[tid] += red[tid + o];
        __syncthreads();
    }
    float inv = 1.0f / red[0];
    #pragma unroll
    for (int i = 0; i < 8; ++i)
        p_out[(size_t)b * S_ + i * 256 + tid] = loc[i] * inv;
}

// ---------- Kernel E: partial expected_ctx over 128-row s-chunks ----------
__global__ __launch_bounds__(256) void k_expected(const float* __restrict__ ctx,
                                                  const float* __restrict__ p,
                                                  float* __restrict__ partial) {
    int b = blockIdx.x, ch = blockIdx.y, tid = threadIdx.x;
    __shared__ float ps[128];
    if (tid < 128) ps[tid] = p[(size_t)b * S_ + ch * 128 + tid];
    __syncthreads();
    const float* base = ctx + ((size_t)b * S_ + ch * 128) * DC + tid * 4;
    float ax = 0.f, ay = 0.f, az = 0.f, aw = 0.f;
    for (int s = 0; s < 128; ++s) {
        const float4 v = *(const float4*)(base + (size_t)s * DC);
        float w = ps[s];
        ax = fmaf(w, v.x, ax);
        ay = fmaf(w, v.y, ay);
        az = fmaf(w, v.z, az);
        aw = fmaf(w, v.w, aw);
    }
    float4 o = { ax, ay, az, aw };
    *(float4*)(partial + ((size_t)(b * 16 + ch)) * DC + tid * 4) = o;
}

// ---------- Kernel R: reduce 16 chunks -> expected_ctx ----------
__global__ __launch_bounds__(256) void k_reduce(const float* __restrict__ partial,
                                                float* __restrict__ out) {
    int b = blockIdx.x, tid = threadIdx.x;
    float4 acc = { 0.f, 0.f, 0.f, 0.f };
    #pragma unroll
    for (int c = 0; c < 16; ++c) {
        const float4 v = *(const float4*)(partial + ((size_t)(b * 16 + c)) * DC + tid * 4);
        acc.x += v.x; acc.y += v.y; acc.z += v.z; acc.w += v.w;
    }
    *(float4*)(out + (size_t)b * DC + tid * 4) = acc;
}

extern "C" void kernel_launch(void* const* d_in, const int* in_sizes, int n_in,
                              void* d_out, int out_size, void* d_ws, size_t ws_size,
                              hipStream_t stream) {
    (void)in_sizes; (void)n_in; (void)out_size; (void)ws_size;
    const float* ctx   = (const float*)d_in[0];
    const float* query = (const float*)d_in[1];
    const float* W1    = (const float*)d_in[2];
    const float* b1    = (const float*)d_in[3];
    const float* W2    = (const float*)d_in[4];
    const float* b2    = (const float*)d_in[5];
    const int*   mask  = (const int*)d_in[6];

    float* out      = (float*)d_out;
    float* expected = out;                 // 32*1024
    float* p_out    = out + 32768;         // 32*2048

    char* w = (char*)d_ws;
    bf16*  WcT        = (bf16*)w;                                   // 1 MB
    float* qb         = (float*)(w + (1 << 20));                    // 64 KB
    float* score_part = (float*)(w + (1 << 20) + (64 << 10));       // 8 x 65536 fp32 = 2 MB
    float* partial_e  = (float*)(w + (3 << 20) + (64 << 10));       // 32*16*1024 fp32 = 2 MB

    k_wconv   <<<2048, 256, 0, stream>>>(W1, WcT);
    k_qb      <<<B_, 512, 0, stream>>>(query, W1, b1, qb);
    k_gemm    <<<dim3(512, 4), 256, 0, stream>>>(ctx, WcT, qb, W2, score_part);
    k_softmax <<<B_, 256, 0, stream>>>(score_part, b2, mask, p_out);
    k_expected<<<dim3(B_, 16), 256, 0, stream>>>(ctx, p_out, partial_e);
    k_reduce  <<<B_, 256, 0, stream>>>(partial_e, expected);
}

// Round 2
// 521.039 us; speedup vs baseline: 1.1861x; 1.1861x over previous
//
#include <hip/hip_runtime.h>

typedef __bf16 bf16;
typedef __attribute__((ext_vector_type(8))) __bf16 bf16x8;
typedef __attribute__((ext_vector_type(4))) __bf16 bf16x4;
typedef __attribute__((ext_vector_type(4))) float f32x4;

#define B_  32
#define S_  2048
#define DC  1024
#define DQ  1024
#define H_  512
#define M_  (B_*S_)        // 65536 flattened (b,s) rows

#define BM  128
#define BN  512            // full H per block -> ctx fetched exactly once
#define BK  32

// async global->LDS, 16B per lane
#define GLD16(g, l) __builtin_amdgcn_global_load_lds( \
    (__attribute__((address_space(1))) void*)(g),     \
    (__attribute__((address_space(3))) void*)(l), 16, 0, 0)

// ---------- Kernel T: Wc (W1[:1024]) -> bf16, tiled [kb][col][kk] (LDS-ready) ----------
// grid 32 (kb), 256 thr. LDS transpose so both global sides are coalesced.
__global__ __launch_bounds__(256) void k_wconv(const float* __restrict__ W1,
                                               bf16* __restrict__ WcT2) {
    __shared__ bf16 t[32 * 520];               // [kk][h], pad 8
    const int kb = blockIdx.x, tid = threadIdx.x;
    #pragma unroll
    for (int i = 0; i < 16; ++i) {
        int base = (i * 256 + tid) * 4;        // 0..16383, h%4==0
        int k = base >> 9;                     // 0..31
        int h = base & 511;
        const float4 v = *(const float4*)(W1 + ((size_t)(kb * 32 + k)) * H_ + h);
        bf16x4 pk = { (bf16)v.x, (bf16)v.y, (bf16)v.z, (bf16)v.w };
        *(bf16x4*)(&t[k * 520 + h]) = pk;
    }
    __syncthreads();
    #pragma unroll
    for (int i = 0; i < 16; ++i) {
        int j = (i * 256 + tid) * 4;           // out idx, kk%4==0
        int col = j >> 5;
        int kk  = j & 31;
        bf16x4 o = { t[kk * 520 + col], t[(kk + 1) * 520 + col],
                     t[(kk + 2) * 520 + col], t[(kk + 3) * 520 + col] };
        *(bf16x4*)(WcT2 + (size_t)kb * 16384 + j) = o;
    }
}

// ---------- Kernel Q: qb[b][h] = query[b,:]·Wq[:,h] + b1[h] (fp32, split-K GEMV) ----------
// grid (8 hblk, 32 b), 256 thr: 64 h x 4 k-chunks.
__global__ __launch_bounds__(256) void k_qb(const float* __restrict__ query,
                                            const float* __restrict__ W1,
                                            const float* __restrict__ b1,
                                            float* __restrict__ qb) {
    const int hblk = blockIdx.x, b = blockIdx.y, tid = threadIdx.x;
    __shared__ float q[DQ];
    __shared__ float red[256];
    #pragma unroll
    for (int i = 0; i < 4; ++i)
        q[tid + i * 256] = query[(size_t)b * DQ + tid + i * 256];
    __syncthreads();
    const int h  = hblk * 64 + (tid & 63);
    const int kc = tid >> 6;                   // 0..3, 256 k each
    const float* w = W1 + (size_t)DC * H_ + (size_t)(kc * 256) * H_ + h;
    const float* qv = q + kc * 256;
    float acc = 0.0f;
    #pragma unroll 8
    for (int k = 0; k < 256; ++k)
        acc = fmaf(qv[k], w[(size_t)k * H_], acc);
    red[tid] = acc;
    __syncthreads();
    if (tid < 64)
        qb[(size_t)b * H_ + hblk * 64 + tid] =
            red[tid] + red[tid + 64] + red[tid + 128] + red[tid + 192] + b1[hblk * 64 + tid];
}

// ---------- Kernel G: score[row] = sum_h tanh(ctx@Wc + qb)[h]*w2[h] ----------
// grid 512 (mblk), 512 thr = 8 waves (2m x 4n), wave tile 64x128, BK=32.
__global__ __launch_bounds__(512, 2) void k_gemm(const float* __restrict__ ctx,
                                                 const bf16*  __restrict__ WcT2,
                                                 const float* __restrict__ qb,
                                                 const float* __restrict__ W2,
                                                 float* __restrict__ score) {
    __shared__ bf16 As[BM * BK];       // 8 KB, unpadded (uniform 8-way b128 reads)
    __shared__ bf16 Bs[BN * BK];       // 32 KB, unpadded (global_load_lds target)
    __shared__ float qs[BN];
    __shared__ float ws2[BN];
    __shared__ float red[BM * 4];

    const int tid  = threadIdx.x;
    const int mblk = blockIdx.x;               // 0..511
    const size_t row_base = (size_t)mblk * BM;
    const int b = mblk >> 4;                   // 16 mblks per batch

    qs[tid]  = qb[(size_t)b * H_ + tid];
    ws2[tid] = W2[tid];

    const int lane = tid & 63;
    const int wave = tid >> 6;                 // 0..7
    const int wm   = wave & 1;                 // 0..1 (x64 rows)
    const int wn   = wave >> 1;                // 0..3 (x128 cols)
    const int l16  = lane & 15;
    const int quad = lane >> 4;

    f32x4 acc[4][8] = {};

    // A staging: thread -> (row, 8k)
    const int am = tid >> 2;                   // 0..127
    const int ak = (tid & 3) << 3;             // 0,8,16,24
    const float* actx = ctx + (row_base + am) * (size_t)DC + ak;
    bf16* awr = &As[am * BK + ak];
    // B staging: contiguous 32KB per kstep via global_load_lds
    const bf16* bsrc = WcT2 + tid * 8;
    bf16* bdst = &Bs[tid * 8];
    // fragment bases
    const bf16* aP = &As[(wm * 64 + l16) * BK + quad * 8];
    const bf16* bP = &Bs[(wn * 128 + l16) * BK + quad * 8];

    for (int kb = 0; kb < DC / BK; ++kb) {
        #pragma unroll
        for (int i = 0; i < 4; ++i)
            GLD16(bsrc + (size_t)kb * 16384 + i * 4096, bdst + i * 4096);
        const float4 v0 = *(const float4*)(actx + kb * BK);
        const float4 v1 = *(const float4*)(actx + kb * BK + 4);
        bf16x8 a8 = { (bf16)v0.x, (bf16)v0.y, (bf16)v0.z, (bf16)v0.w,
                      (bf16)v1.x, (bf16)v1.y, (bf16)v1.z, (bf16)v1.w };
        *(bf16x8*)awr = a8;
        __syncthreads();

        bf16x8 aF[4], bF[8];
        #pragma unroll
        for (int mf = 0; mf < 4; ++mf) aF[mf] = *(const bf16x8*)(aP + mf * (16 * BK));
        #pragma unroll
        for (int nf = 0; nf < 8; ++nf) bF[nf] = *(const bf16x8*)(bP + nf * (16 * BK));
        #pragma unroll
        for (int mf = 0; mf < 4; ++mf)
            #pragma unroll
            for (int nf = 0; nf < 8; ++nf)
                acc[mf][nf] = __builtin_amdgcn_mfma_f32_16x16x32_bf16(aF[mf], bF[nf], acc[mf][nf], 0, 0, 0);
        __syncthreads();
    }

    // Epilogue: s(row) = sum over this wave's 128 cols of tanh(acc+qb)*w2
    float qv[8], wv[8];
    #pragma unroll
    for (int nf = 0; nf < 8; ++nf) {
        int c = wn * 128 + nf * 16 + l16;
        qv[nf] = qs[c];
        wv[nf] = ws2[c];
    }
    #pragma unroll
    for (int mf = 0; mf < 4; ++mf) {
        #pragma unroll
        for (int r = 0; r < 4; ++r) {
            float s = 0.0f;
            #pragma unroll
            for (int nf = 0; nf < 8; ++nf) {
                float x = acc[mf][nf][r] + qv[nf];
                float t = 1.0f - 2.0f / (1.0f + __expf(2.0f * x)); // tanh, saturates
                s = fmaf(t, wv[nf], s);
            }
            s += __shfl_xor(s, 1);
            s += __shfl_xor(s, 2);
            s += __shfl_xor(s, 4);
            s += __shfl_xor(s, 8);
            if (l16 == 0)
                red[(wm * 64 + mf * 16 + quad * 4 + r) * 4 + wn] = s;
        }
    }
    __syncthreads();
    if (tid < BM)
        score[row_base + tid] = red[tid * 4] + red[tid * 4 + 1] + red[tid * 4 + 2] + red[tid * 4 + 3];
}

// ---------- Kernel S: + b2, mask, stable softmax per batch row ----------
__global__ __launch_bounds__(256) void k_softmax(const float* __restrict__ score,
                                                 const float* __restrict__ b2,
                                                 const int*   __restrict__ mask,
                                                 float* __restrict__ p_out) {
    int b = blockIdx.x, tid = threadIdx.x;
    __shared__ float red[256];
    float loc[8];
    float b2v = b2[0];
    float mx = -1e30f;
    #pragma unroll
    for (int i = 0; i < 8; ++i) {
        size_t r = (size_t)b * S_ + i * 256 + tid;
        float v = score[r] + b2v;
        if (mask[r] == 0) v = -10000.0f;
        loc[i] = v;
        mx = fmaxf(mx, v);
    }
    red[tid] = mx; __syncthreads();
    for (int o = 128; o > 0; o >>= 1) {
        if (tid < o) red[tid] = fmaxf(red[tid], red[tid + o]);
        __syncthreads();
    }
    mx = red[0]; __syncthreads();
    float se = 0.0f;
    #pragma unroll
    for (int i = 0; i < 8; ++i) {
        float e = __expf(loc[i] - mx);
        loc[i] = e;
        se += e;
    }
    red[tid] = se; __syncthreads();
    for (int o = 128; o > 0; o >>= 1) {
        if (tid < o) red[tid] += red[tid + o];
        __syncthreads();
    }
    float inv = 1.0f / red[0];
    #pragma unroll
    for (int i = 0; i < 8; ++i)
        p_out[(size_t)b * S_ + i * 256 + tid] = loc[i] * inv;
}

// ---------- Kernel E: partial expected_ctx over 128-row s-chunks ----------
__global__ __launch_bounds__(256) void k_expected(const float* __restrict__ ctx,
                                                  const float* __restrict__ p,
                                                  float* __restrict__ partial) {
    int b = blockIdx.x, ch = blockIdx.y, tid = threadIdx.x;
    __shared__ float ps[128];
    if (tid < 128) ps[tid] = p[(size_t)b * S_ + ch * 128 + tid];
    __syncthreads();
    const float* base = ctx + ((size_t)b * S_ + ch * 128) * DC + tid * 4;
    float ax = 0.f, ay = 0.f, az = 0.f, aw = 0.f;
    #pragma unroll 4
    for (int s = 0; s < 128; ++s) {
        const float4 v = *(const float4*)(base + (size_t)s * DC);
        float w = ps[s];
        ax = fmaf(w, v.x, ax);
        ay = fmaf(w, v.y, ay);
        az = fmaf(w, v.z, az);
        aw = fmaf(w, v.w, aw);
    }
    float4 o = { ax, ay, az, aw };
    *(float4*)(partial + ((size_t)(b * 16 + ch)) * DC + tid * 4) = o;
}

// ---------- Kernel R: reduce 16 chunks -> expected_ctx ----------
__global__ __launch_bounds__(256) void k_reduce(const float* __restrict__ partial,
                                                float* __restrict__ out) {
    int b = blockIdx.x, tid = threadIdx.x;
    float4 acc = { 0.f, 0.f, 0.f, 0.f };
    #pragma unroll
    for (int c = 0; c < 16; ++c) {
        const float4 v = *(const float4*)(partial + ((size_t)(b * 16 + c)) * DC + tid * 4);
        acc.x += v.x; acc.y += v.y; acc.z += v.z; acc.w += v.w;
    }
    *(float4*)(out + (size_t)b * DC + tid * 4) = acc;
}

extern "C" void kernel_launch(void* const* d_in, const int* in_sizes, int n_in,
                              void* d_out, int out_size, void* d_ws, size_t ws_size,
                              hipStream_t stream) {
    (void)in_sizes; (void)n_in; (void)out_size; (void)ws_size;
    const float* ctx   = (const float*)d_in[0];
    const float* query = (const float*)d_in[1];
    const float* W1    = (const float*)d_in[2];
    const float* b1    = (const float*)d_in[3];
    const float* W2    = (const float*)d_in[4];
    const float* b2    = (const float*)d_in[5];
    const int*   mask  = (const int*)d_in[6];

    float* out      = (float*)d_out;
    float* expected = out;                 // 32*1024
    float* p_out    = out + 32768;         // 32*2048

    char* w = (char*)d_ws;
    bf16*  WcT2      = (bf16*)w;                                    // 1 MB  [kb][col][kk]
    float* qb        = (float*)(w + (1 << 20));                     // 64 KB
    float* score     = (float*)(w + (1 << 20) + (64 << 10));        // 256 KB
    float* partial_e = (float*)(w + (1 << 20) + (320 << 10));       // 2 MB

    k_wconv   <<<32, 256, 0, stream>>>(W1, WcT2);
    k_qb      <<<dim3(8, B_), 256, 0, stream>>>(query, W1, b1, qb);
    k_gemm    <<<512, 512, 0, stream>>>(ctx, WcT2, qb, W2, score);
    k_softmax <<<B_, 256, 0, stream>>>(score, b2, mask, p_out);
    k_expected<<<dim3(B_, 16), 256, 0, stream>>>(ctx, p_out, partial_e);
    k_reduce  <<<B_, 256, 0, stream>>>(partial_e, expected);
}

// Round 3
// 493.932 us; speedup vs baseline: 1.2512x; 1.0549x over previous
//
#include <hip/hip_runtime.h>

typedef __bf16 bf16;
typedef __attribute__((ext_vector_type(8))) __bf16 bf16x8;
typedef __attribute__((ext_vector_type(4))) __bf16 bf16x4;
typedef __attribute__((ext_vector_type(4))) float f32x4;

#define B_  32
#define S_  2048
#define DC  1024
#define DQ  1024
#define H_  512
#define M_  (B_*S_)

#define BM  128
#define BN  512            // full H per block -> ctx fetched exactly once
#define BK  32
#define NCH 32             // s-chunks for expected_ctx

// async global->LDS, 16B per lane
#define GLD16(g, l) __builtin_amdgcn_global_load_lds( \
    (__attribute__((address_space(1))) void*)(g),     \
    (__attribute__((address_space(3))) void*)(l), 16, 0, 0)

// ---------- Prep: blocks 0..255 = Wc->bf16 transpose tiles; 256..511 = qb GEMV ----------
__global__ __launch_bounds__(256) void k_prep(const float* __restrict__ W1,
                                              const float* __restrict__ query,
                                              const float* __restrict__ b1,
                                              bf16* __restrict__ WcT2,
                                              float* __restrict__ qb) {
    const int bid = blockIdx.x, tid = threadIdx.x;
    if (bid < 256) {
        // W1[:1024] (k-major) -> WcT2 [kb(32)][col(512)][kk(32)] bf16
        __shared__ bf16 t[32 * 68];            // [kk][h-in-tile], pad 4
        const int kb = bid >> 3;               // 0..31
        const int cb = bid & 7;                // 0..7, 64-col tile
        #pragma unroll
        for (int i = 0; i < 2; ++i) {
            int idx = i * 256 + tid;           // 0..511
            int k  = idx >> 4;                 // 0..31
            int h4 = (idx & 15) * 4;           // 0..60
            const float4 v = *(const float4*)(W1 + ((size_t)(kb * 32 + k)) * H_ + cb * 64 + h4);
            bf16x4 pk = { (bf16)v.x, (bf16)v.y, (bf16)v.z, (bf16)v.w };
            *(bf16x4*)(&t[k * 68 + h4]) = pk;
        }
        __syncthreads();
        const int col = tid >> 2;              // 0..63
        const int kk0 = (tid & 3) * 8;         // 0,8,16,24
        bf16x8 o;
        #pragma unroll
        for (int j = 0; j < 8; ++j) o[j] = t[(kk0 + j) * 68 + col];
        *(bf16x8*)(WcT2 + (size_t)kb * 16384 + (size_t)(cb * 64 + col) * 32 + kk0) = o;
    } else {
        // qb[b][h] = query[b,:] . Wq[:,h] + b1[h]
        const int r = bid - 256;
        const int hblk = r & 7;                // 0..7
        const int b    = r >> 3;               // 0..31
        __shared__ float q[DQ];
        __shared__ float red[256];
        #pragma unroll
        for (int i = 0; i < 4; ++i)
            q[tid + i * 256] = query[(size_t)b * DQ + tid + i * 256];
        __syncthreads();
        const int h  = hblk * 64 + (tid & 63);
        const int kc = tid >> 6;               // 0..3
        const float* w = W1 + (size_t)DC * H_ + (size_t)(kc * 256) * H_ + h;
        const float* qv = q + kc * 256;
        float acc = 0.0f;
        #pragma unroll 8
        for (int k = 0; k < 256; ++k)
            acc = fmaf(qv[k], w[(size_t)k * H_], acc);
        red[tid] = acc;
        __syncthreads();
        if (tid < 64)
            qb[(size_t)b * H_ + hblk * 64 + tid] =
                red[tid] + red[tid + 64] + red[tid + 128] + red[tid + 192] + b1[hblk * 64 + tid];
    }
}

// ---------- Kernel G: score[row] = sum_h tanh(ctx@Wc + qb)[h]*w2[h] ----------
// 512 blocks, 512 thr = 8 waves (2m x 4n), wave tile 64x128.
// Double-buffered LDS, ONE barrier per k-step; loads for k+1 issued right
// after the barrier so the whole MFMA phase hides their latency.
__global__ __launch_bounds__(512) void k_gemm(const float* __restrict__ ctx,
                                              const bf16*  __restrict__ WcT2,
                                              const float* __restrict__ qb,
                                              const float* __restrict__ W2,
                                              float* __restrict__ score) {
    __shared__ char smem_raw[81920];
    bf16* As = (bf16*)smem_raw;                // [2][128*32]  16 KB
    bf16* Bs = (bf16*)(smem_raw + 16384);      // [2][512*32]  64 KB
    float* red = (float*)smem_raw;             // epilogue reuse of As region

    const int tid  = threadIdx.x;
    const int mblk = blockIdx.x;
    const size_t row_base = (size_t)mblk * BM;
    const int b = mblk >> 4;

    const int lane = tid & 63;
    const int wave = tid >> 6;
    const int wm   = wave & 1;
    const int wn   = wave >> 1;
    const int l16  = lane & 15;
    const int quad = lane >> 4;

    f32x4 acc[4][8] = {};

    const int am = tid >> 2;                   // 0..127
    const int ak = (tid & 3) << 3;             // 0,8,16,24
    const float* actx = ctx + (row_base + am) * (size_t)DC + ak;
    const int aoff = am * BK + ak;
    const bf16* bsrc = WcT2 + tid * 8;
    const int boff = tid * 8;
    const int fA = (wm * 64 + l16) * BK + quad * 8;
    const int fB = (wn * 128 + l16) * BK + quad * 8;

    // ---- prologue: stage k-step 0 into buffer 0 ----
    {
        const float4 v0 = *(const float4*)(actx);
        const float4 v1 = *(const float4*)(actx + 4);
        bf16x8 a8 = { (bf16)v0.x, (bf16)v0.y, (bf16)v0.z, (bf16)v0.w,
                      (bf16)v1.x, (bf16)v1.y, (bf16)v1.z, (bf16)v1.w };
        *(bf16x8*)(As + aoff) = a8;
        #pragma unroll
        for (int i = 0; i < 4; ++i)
            GLD16(bsrc + i * 4096, Bs + boff + i * 4096);
    }
    __syncthreads();

    for (int kb = 0; kb < DC / BK; ++kb) {
        const int cur = kb & 1, nxt = cur ^ 1;
        float4 av0, av1;
        if (kb < 31) {
            #pragma unroll
            for (int i = 0; i < 4; ++i)
                GLD16(bsrc + (size_t)(kb + 1) * 16384 + i * 4096,
                      Bs + nxt * 16384 + boff + i * 4096);
            av0 = *(const float4*)(actx + (kb + 1) * BK);
            av1 = *(const float4*)(actx + (kb + 1) * BK + 4);
        }

        bf16x8 aF[4], bF[8];
        const bf16* aP = As + cur * 4096 + fA;
        const bf16* bP = Bs + cur * 16384 + fB;
        #pragma unroll
        for (int mf = 0; mf < 4; ++mf) aF[mf] = *(const bf16x8*)(aP + mf * (16 * BK));
        #pragma unroll
        for (int nf = 0; nf < 8; ++nf) bF[nf] = *(const bf16x8*)(bP + nf * (16 * BK));
        #pragma unroll
        for (int mf = 0; mf < 4; ++mf)
            #pragma unroll
            for (int nf = 0; nf < 8; ++nf)
                acc[mf][nf] = __builtin_amdgcn_mfma_f32_16x16x32_bf16(aF[mf], bF[nf], acc[mf][nf], 0, 0, 0);

        if (kb < 31) {
            bf16x8 a8 = { (bf16)av0.x, (bf16)av0.y, (bf16)av0.z, (bf16)av0.w,
                          (bf16)av1.x, (bf16)av1.y, (bf16)av1.z, (bf16)av1.w };
            *(bf16x8*)(As + nxt * 4096 + aoff) = a8;
        }
        __syncthreads();
    }

    // ---- epilogue: s(row) = sum over this wave's 128 cols of tanh(acc+qb)*w2 ----
    float qv[8], wv[8];
    #pragma unroll
    for (int nf = 0; nf < 8; ++nf) {
        int c = wn * 128 + nf * 16 + l16;
        qv[nf] = qb[(size_t)b * H_ + c];
        wv[nf] = W2[c];
    }
    #pragma unroll
    for (int mf = 0; mf < 4; ++mf) {
        #pragma unroll
        for (int r = 0; r < 4; ++r) {
            float s = 0.0f;
            #pragma unroll
            for (int nf = 0; nf < 8; ++nf) {
                float x = acc[mf][nf][r] + qv[nf];
                float t = 1.0f - 2.0f / (1.0f + __expf(2.0f * x)); // tanh, saturates
                s = fmaf(t, wv[nf], s);
            }
            s += __shfl_xor(s, 1);
            s += __shfl_xor(s, 2);
            s += __shfl_xor(s, 4);
            s += __shfl_xor(s, 8);
            if (l16 == 0)
                red[(wm * 64 + mf * 16 + quad * 4 + r) * 4 + wn] = s;
        }
    }
    __syncthreads();
    if (tid < BM)
        score[row_base + tid] = red[tid * 4] + red[tid * 4 + 1] + red[tid * 4 + 2] + red[tid * 4 + 3];
}

// ---------- Kernel S: + b2, mask, stable softmax per batch row ----------
__global__ __launch_bounds__(256) void k_softmax(const float* __restrict__ score,
                                                 const float* __restrict__ b2,
                                                 const int*   __restrict__ mask,
                                                 float* __restrict__ p_out) {
    int b = blockIdx.x, tid = threadIdx.x;
    __shared__ float red[256];
    float loc[8];
    float b2v = b2[0];
    float mx = -1e30f;
    #pragma unroll
    for (int i = 0; i < 8; ++i) {
        size_t r = (size_t)b * S_ + i * 256 + tid;
        float v = score[r] + b2v;
        if (mask[r] == 0) v = -10000.0f;
        loc[i] = v;
        mx = fmaxf(mx, v);
    }
    red[tid] = mx; __syncthreads();
    for (int o = 128; o > 0; o >>= 1) {
        if (tid < o) red[tid] = fmaxf(red[tid], red[tid + o]);
        __syncthreads();
    }
    mx = red[0]; __syncthreads();
    float se = 0.0f;
    #pragma unroll
    for (int i = 0; i < 8; ++i) {
        float e = __expf(loc[i] - mx);
        loc[i] = e;
        se += e;
    }
    red[tid] = se; __syncthreads();
    for (int o = 128; o > 0; o >>= 1) {
        if (tid < o) red[tid] += red[tid + o];
        __syncthreads();
    }
    float inv = 1.0f / red[0];
    #pragma unroll
    for (int i = 0; i < 8; ++i)
        p_out[(size_t)b * S_ + i * 256 + tid] = loc[i] * inv;
}

// ---------- Kernel E: partial expected_ctx over 64-row s-chunks ----------
__global__ __launch_bounds__(256) void k_expected(const float* __restrict__ ctx,
                                                  const float* __restrict__ p,
                                                  float* __restrict__ partial) {
    int b = blockIdx.x, ch = blockIdx.y, tid = threadIdx.x;
    __shared__ float ps[64];
    if (tid < 64) ps[tid] = p[(size_t)b * S_ + ch * 64 + tid];
    __syncthreads();
    const float* base = ctx + ((size_t)b * S_ + ch * 64) * DC + tid * 4;
    float ax = 0.f, ay = 0.f, az = 0.f, aw = 0.f;
    #pragma unroll 8
    for (int s = 0; s < 64; ++s) {
        const float4 v = *(const float4*)(base + (size_t)s * DC);
        float w = ps[s];
        ax = fmaf(w, v.x, ax);
        ay = fmaf(w, v.y, ay);
        az = fmaf(w, v.z, az);
        aw = fmaf(w, v.w, aw);
    }
    float4 o = { ax, ay, az, aw };
    *(float4*)(partial + ((size_t)(b * NCH + ch)) * DC + tid * 4) = o;
}

// ---------- Kernel R: reduce chunks -> expected_ctx ----------
__global__ __launch_bounds__(256) void k_reduce(const float* __restrict__ partial,
                                                float* __restrict__ out) {
    int b = blockIdx.x, tid = threadIdx.x;
    float4 acc = { 0.f, 0.f, 0.f, 0.f };
    #pragma unroll
    for (int c = 0; c < NCH; ++c) {
        const float4 v = *(const float4*)(partial + ((size_t)(b * NCH + c)) * DC + tid * 4);
        acc.x += v.x; acc.y += v.y; acc.z += v.z; acc.w += v.w;
    }
    *(float4*)(out + (size_t)b * DC + tid * 4) = acc;
}

extern "C" void kernel_launch(void* const* d_in, const int* in_sizes, int n_in,
                              void* d_out, int out_size, void* d_ws, size_t ws_size,
                              hipStream_t stream) {
    (void)in_sizes; (void)n_in; (void)out_size; (void)ws_size;
    const float* ctx   = (const float*)d_in[0];
    const float* query = (const float*)d_in[1];
    const float* W1    = (const float*)d_in[2];
    const float* b1    = (const float*)d_in[3];
    const float* W2    = (const float*)d_in[4];
    const float* b2    = (const float*)d_in[5];
    const int*   mask  = (const int*)d_in[6];

    float* out      = (float*)d_out;
    float* expected = out;                 // 32*1024
    float* p_out    = out + 32768;         // 32*2048

    char* w = (char*)d_ws;
    bf16*  WcT2      = (bf16*)w;                                    // 1 MB  [kb][col][kk]
    float* qb        = (float*)(w + (1 << 20));                     // 64 KB
    float* score     = (float*)(w + (1 << 20) + (64 << 10));        // 256 KB
    float* partial_e = (float*)(w + (1 << 20) + (320 << 10));       // 4 MB

    k_prep    <<<512, 256, 0, stream>>>(W1, query, b1, WcT2, qb);
    k_gemm    <<<512, 512, 0, stream>>>(ctx, WcT2, qb, W2, score);
    k_softmax <<<B_, 256, 0, stream>>>(score, b2, mask, p_out);
    k_expected<<<dim3(B_, NCH), 256, 0, stream>>>(ctx, p_out, partial_e);
    k_reduce  <<<B_, 256, 0, stream>>>(partial_e, expected);
}